// Round 3
// baseline (623.597 us; speedup 1.0000x reference)
//
#include <hip/hip_runtime.h>
#include <hip/hip_bf16.h>
#include <math.h>

// Problem constants
#define BB 32
#define TT 512
#define HH 2048
#define KK 128
#define CH 8    // scan chunk (steps per emission-prefetch chunk)
#define NC 32   // chunks per HALF-scan (alpha/beta): 32*8 = 256 steps
#define NCV 64  // chunks for FULL viterbi scan: 64*8 = 512 steps

// workspace layout (bytes) — total exactly 18,874,368 (proven safe size)
#define WS_LOGITS 0
#define WS_SHIST  8388608u
#define WS_BP     16777216u
// seam scratch lives in the OUTPUT buffer's decode rows (dead until bt_k):
//   out[b*TT + 0..127]   seamA_b  (alpha_255, exp2 domain, normalized)
//   out[b*TT + 128..255] seamB_b  (beta_255,  exp2 domain, normalized)
//   out[b*TT + 384]      OFF_A    out[b*TT+385] OFF_B   out[b*TT+386] score

// DPP quad-lane reductions (lanes tid&3 = 0..3 hold k-slice partials).
__device__ __forceinline__ float quad_add(float x) {
    int a = __builtin_amdgcn_update_dpp(0, __float_as_int(x), 0xB1, 0xF, 0xF, true);
    x += __int_as_float(a);
    int b = __builtin_amdgcn_update_dpp(0, __float_as_int(x), 0x4E, 0xF, 0xF, true);
    x += __int_as_float(b);
    return x;
}
__device__ __forceinline__ float quad_max(float x) {
    int a = __builtin_amdgcn_update_dpp(0, __float_as_int(x), 0xB1, 0xF, 0xF, true);
    x = fmaxf(x, __int_as_float(a));
    int b = __builtin_amdgcn_update_dpp(0, __float_as_int(x), 0x4E, 0xF, 0xF, true);
    x = fmaxf(x, __int_as_float(b));
    return x;
}

// lgkm-only barrier: orders LDS write->read across waves WITHOUT draining
// vmcnt, so per-chunk emission prefetches / history stores stay in flight
// across steps (__syncthreads would emit s_waitcnt vmcnt(0) every step).
// sched_barrier(0) fences prevent compiler motion across the asm (rule #18).
__device__ __forceinline__ void step_barrier() {
    __builtin_amdgcn_sched_barrier(0);
    asm volatile("s_waitcnt lgkmcnt(0)" ::: "memory");
    __builtin_amdgcn_sched_barrier(0);
    __builtin_amdgcn_s_barrier();
    __builtin_amdgcn_sched_barrier(0);
}

// -------------------- Kernel A: logits = hiddens @ W + b --------------------
// 256 blocks x 512 threads, in-block split-K (4 wave-groups x K=512).
__global__ __launch_bounds__(512) void gemm_k(const float* __restrict__ hid,
                                              const float* __restrict__ Wm,
                                              const float* __restrict__ bias,
                                              float* __restrict__ logits,
                                              float* __restrict__ loss_slot) {
    __shared__ union {
        struct { float As[4][16][72]; float Bs[4][16][132]; } s;  // 52.2 KB
        float4 red[16][128];                                      // 32 KB
    } sm;
    const int tid = threadIdx.x, bid = blockIdx.x;
    if (bid == 0 && tid == 0) loss_slot[0] = 0.0f;
    const int g = tid >> 7, lt = tid & 127;
    const int rowBase = bid * 64;
    const int rowg = lt >> 4, colg = lt & 15;
    const int arow = lt >> 1, ahq = lt & 1;  // A staging: row, h-half

    float acc[8][8];
#pragma unroll
    for (int i = 0; i < 8; i++)
#pragma unroll
        for (int j = 0; j < 8; j++) acc[i][j] = 0.0f;

    const float* hA = hid + (size_t)(rowBase + arow) * HH + g * 512 + ahq * 8;

    float4 a0, a1, bv[4];
    {
        const int h0 = g * 512;
        a0 = *(const float4*)(hA);
        a1 = *(const float4*)(hA + 4);
#pragma unroll
        for (int r = 0; r < 4; ++r) {
            int idx = r * 128 + lt;
            bv[r] = *(const float4*)(Wm + (size_t)(h0 + (idx >> 5)) * KK + (idx & 31) * 4);
        }
    }

    for (int it = 0; it < 32; ++it) {
        __syncthreads();
        const int hb = ahq * 8;
        sm.s.As[g][hb + 0][arow] = a0.x;
        sm.s.As[g][hb + 1][arow] = a0.y;
        sm.s.As[g][hb + 2][arow] = a0.z;
        sm.s.As[g][hb + 3][arow] = a0.w;
        sm.s.As[g][hb + 4][arow] = a1.x;
        sm.s.As[g][hb + 5][arow] = a1.y;
        sm.s.As[g][hb + 6][arow] = a1.z;
        sm.s.As[g][hb + 7][arow] = a1.w;
#pragma unroll
        for (int r = 0; r < 4; ++r) {
            int idx = r * 128 + lt;
            *(float4*)&sm.s.Bs[g][idx >> 5][(idx & 31) * 4] = bv[r];
        }
        __syncthreads();
        if (it + 1 < 32) {
            const int h0 = g * 512 + (it + 1) * 16;
            a0 = *(const float4*)(hA + (it + 1) * 16);
            a1 = *(const float4*)(hA + (it + 1) * 16 + 4);
#pragma unroll
            for (int r = 0; r < 4; ++r) {
                int idx = r * 128 + lt;
                bv[r] = *(const float4*)(Wm + (size_t)(h0 + (idx >> 5)) * KK + (idx & 31) * 4);
            }
        }
#pragma unroll
        for (int h = 0; h < 16; ++h) {
            float4 aL = *(const float4*)&sm.s.As[g][h][rowg * 8];
            float4 aH = *(const float4*)&sm.s.As[g][h][rowg * 8 + 4];
            float4 b0 = *(const float4*)&sm.s.Bs[g][h][colg * 4];
            float4 b1 = *(const float4*)&sm.s.Bs[g][h][64 + colg * 4];
            float ar[8] = {aL.x, aL.y, aL.z, aL.w, aH.x, aH.y, aH.z, aH.w};
            float br[8] = {b0.x, b0.y, b0.z, b0.w, b1.x, b1.y, b1.z, b1.w};
#pragma unroll
            for (int i = 0; i < 8; i++)
#pragma unroll
                for (int j = 0; j < 8; j++) acc[i][j] = fmaf(ar[i], br[j], acc[i][j]);
        }
    }
    __syncthreads();
    for (int gp = 1; gp <= 3; ++gp) {
        if (g == gp) {
#pragma unroll
            for (int i = 0; i < 8; ++i) {
                sm.red[i * 2][lt] = make_float4(acc[i][0], acc[i][1], acc[i][2], acc[i][3]);
                sm.red[i * 2 + 1][lt] = make_float4(acc[i][4], acc[i][5], acc[i][6], acc[i][7]);
            }
        }
        __syncthreads();
        if (g == 0) {
#pragma unroll
            for (int i = 0; i < 8; ++i) {
                float4 r0 = sm.red[i * 2][lt];
                float4 r1 = sm.red[i * 2 + 1][lt];
                acc[i][0] += r0.x; acc[i][1] += r0.y; acc[i][2] += r0.z; acc[i][3] += r0.w;
                acc[i][4] += r1.x; acc[i][5] += r1.y; acc[i][6] += r1.z; acc[i][7] += r1.w;
            }
        }
        __syncthreads();
    }
    if (g == 0) {
        float4 bb0 = *(const float4*)(bias + colg * 4);
        float4 bb1 = *(const float4*)(bias + 64 + colg * 4);
#pragma unroll
        for (int i = 0; i < 8; ++i) {
            int row = rowBase + rowg * 8 + i;
            *(float4*)(logits + (size_t)row * KK + colg * 4) =
                make_float4(acc[i][0] + bb0.x, acc[i][1] + bb0.y, acc[i][2] + bb0.z, acc[i][3] + bb0.w);
            *(float4*)(logits + (size_t)row * KK + 64 + colg * 4) =
                make_float4(acc[i][4] + bb1.x, acc[i][5] + bb1.y, acc[i][6] + bb1.z, acc[i][7] + bb1.w);
        }
    }
}

// -------------------- Kernel B: scans ---------------------------------------
// 96 blocks x 256 threads.
//   bid [0,32):  alpha forward  t=0..255   (+ gold score, seamA, OFF_A)
//   bid [32,64): beta backward  t=511..256 (seamB, OFF_B)
//   bid [64,96): viterbi forward t=0..511  (FULL chain — exact decode)
// Thread (jb=tid>>2, s=tid&3) owns states {2jb,2jb+1}, k-slice [32s,32s+32).
// Cross-slice reduction via DPP quad_perm; cross-wave state via LDS ubuf
// (double-buffered) + lgkm-only step_barrier.
struct SMemB {
    float ubuf[2][144];
    float red[4];
};

__global__ __launch_bounds__(256, 1) void scan_k(const float* __restrict__ logits,
                                                 const int* __restrict__ mask,
                                                 const int* __restrict__ labels,
                                                 const float* __restrict__ startT,
                                                 const float* __restrict__ endT,
                                                 const float* __restrict__ trans,
                                                 float* __restrict__ shist,
                                                 float* __restrict__ out) {
    __shared__ SMemB sm;
    const int tid = threadIdx.x;
    const int bid = blockIdx.x;
    const float L2E = 1.4426950408889634f;
    const int s = tid & 3;
    const int jb = tid >> 2;
    const int j0 = jb * 2;
    const int padw = j0 + 4 * (j0 >> 5);
    const int lane = tid & 63;

    if (bid < BB) {
        // ---------- forward alpha (exp domain), t = 0..255 ----------
        const int b = bid;
        const float* lrow = logits + (size_t)b * TT * KK;
        unsigned long long mb[8];
#pragma unroll
        for (int c = 0; c < 8; ++c) mb[c] = __ballot(mask[b * TT + c * 64 + lane] != 0);
        float V0[32], V1[32];
#pragma unroll
        for (int k = 0; k < 32; k++) {
            V0[k] = exp2f(trans[(s * 32 + k) * KK + j0] * L2E);
            V1[k] = exp2f(trans[(s * 32 + k) * KK + j0 + 1] * L2E);
        }
        float a0_ = (startT[j0] + lrow[j0]) * L2E;
        float a1_ = (startT[j0 + 1] + lrow[j0 + 1]) * L2E;
        float OFF = (startT[0] + lrow[0]) * L2E;  // identical on all threads
        float S0_ = exp2f(a0_ - OFF);
        float S1_ = exp2f(a1_ - OFF);
        if (s == 0) {
            sm.ubuf[0][padw] = S0_;
            sm.ubuf[0][padw + 1] = S1_;
        }
        float2 emc[CH], emn[CH];
#pragma unroll
        for (int d = 0; d < CH; ++d) emc[d] = *(const float2*)(lrow + (size_t)d * KK + j0);
        __syncthreads();
        int cur = 0;
        for (int c = 0; c < NC; ++c) {
#pragma unroll
            for (int r = 0; r < CH; ++r) {
                const int t = c * CH + r;
                if (r == 0 && c + 1 < NC) {
#pragma unroll
                    for (int d = 0; d < CH; ++d)
                        emn[d] = *(const float2*)(lrow + (size_t)((c + 1) * CH + d) * KK + j0);
                }
                if (t > 0 && ((mb[t >> 6] >> (t & 63)) & 1ull)) {
                    const float* ub = &sm.ubuf[cur][s * 36];
                    float u00 = sm.ubuf[cur][0];
                    float uu[32];
#pragma unroll
                    for (int cc = 0; cc < 8; ++cc) {
                        float4 v = *(const float4*)(ub + cc * 4);
                        uu[cc * 4] = v.x; uu[cc * 4 + 1] = v.y; uu[cc * 4 + 2] = v.z; uu[cc * 4 + 3] = v.w;
                    }
                    float2 em = emc[r];
                    float p0e = 0.f, p0o = 0.f, p1e = 0.f, p1o = 0.f;
#pragma unroll
                    for (int k = 0; k < 32; k += 2) {
                        p0e = fmaf(uu[k], V0[k], p0e);
                        p1e = fmaf(uu[k], V1[k], p1e);
                        p0o = fmaf(uu[k + 1], V0[k + 1], p0o);
                        p1o = fmaf(uu[k + 1], V1[k + 1], p1o);
                    }
                    float w0 = quad_add(p0e + p0o);
                    float w1 = quad_add(p1e + p1o);
                    float rinv = __builtin_amdgcn_rcpf(u00);
                    OFF += log2f(u00);
                    S0_ = w0 * (exp2f(em.x * L2E) * rinv);
                    S1_ = w1 * (exp2f(em.y * L2E) * rinv);
                    if (s == 0) {
                        sm.ubuf[cur ^ 1][padw] = S0_;
                        sm.ubuf[cur ^ 1][padw + 1] = S1_;
                    }
                    cur ^= 1;
                }
                step_barrier();
            }
#pragma unroll
            for (int d = 0; d < CH; ++d) emc[d] = emn[d];
        }
        // seam state (alpha_255 in exp domain) + offset -> out scratch
        if (s == 0) {
            out[b * TT + j0] = S0_;
            out[b * TT + j0 + 1] = S1_;
        }
        if (tid == 0) out[b * TT + 384] = OFF;

        // gold path score (parallel over t, full range)
        float part = 0.0f;
        for (int tt = tid; tt < TT; tt += 256) {
            if (tt == 0) {
                int l0 = labels[b * TT];
                part += startT[l0] + lrow[l0];
            } else if (mask[b * TT + tt]) {
                int lc = labels[b * TT + tt];
                int lp = labels[b * TT + tt - 1];
                part += trans[lp * KK + lc] + lrow[(size_t)tt * KK + lc];
            }
        }
#pragma unroll
        for (int d = 1; d < 64; d <<= 1) part += __shfl_xor(part, d, 64);
        int wid = tid >> 6;
        if (lane == 0) sm.red[wid] = part;
        __syncthreads();
        if (tid == 0) {
            int total = 0;
#pragma unroll
            for (int c = 0; c < 8; ++c) total += __popcll(mb[c]);
            float score = sm.red[0] + sm.red[1] + sm.red[2] + sm.red[3];
            score += endT[labels[b * TT + total - 1]];
            out[b * TT + 386] = score;
        }
    } else if (bid < 2 * BB) {
        // ---------- backward beta (exp domain), steps t = 511..256 ----------
        // LDS holds y_j = exp(e_t[j]) * B_j (rewritten every step: e changes).
        const int b = bid - BB;
        const float* lrow = logits + (size_t)b * TT * KK;
        unsigned long long mb[4];
#pragma unroll
        for (int c = 0; c < 4; ++c) mb[c] = __ballot(mask[b * TT + 256 + c * 64 + lane] != 0);
        float V0[32], V1[32];   // rows of exp(trans): E[j0][k], E[j0+1][k]
#pragma unroll
        for (int k = 0; k < 32; k++) {
            V0[k] = exp2f(trans[j0 * KK + s * 32 + k] * L2E);
            V1[k] = exp2f(trans[(j0 + 1) * KK + s * 32 + k] * L2E);
        }
        float OFF = endT[0] * L2E;
        float S0_ = exp2f(endT[j0] * L2E - OFF);
        float S1_ = exp2f(endT[j0 + 1] * L2E - OFF);
        {
            float2 e511 = *(const float2*)(lrow + (size_t)511 * KK + j0);
            if (s == 0) {
                sm.ubuf[0][padw] = exp2f(e511.x * L2E) * S0_;
                sm.ubuf[0][padw + 1] = exp2f(e511.y * L2E) * S1_;
            }
        }
        float2 emc[CH], emn[CH];
#pragma unroll
        for (int d = 0; d < CH; ++d) emc[d] = *(const float2*)(lrow + (size_t)(510 - d) * KK + j0);
        __syncthreads();
        int cur = 0;
        for (int c = 0; c < NC; ++c) {
#pragma unroll
            for (int r = 0; r < CH; ++r) {
                const int t = 511 - (c * CH + r);
                if (r == 0 && c + 1 < NC) {
#pragma unroll
                    for (int d = 0; d < CH; ++d)
                        emn[d] = *(const float2*)(lrow + (size_t)(510 - (c + 1) * CH - d) * KK + j0);
                }
                if ((mb[(t - 256) >> 6] >> ((t - 256) & 63)) & 1ull) {
                    const float* ub = &sm.ubuf[cur][s * 36];
                    float u00 = sm.ubuf[cur][0];
                    float uu[32];
#pragma unroll
                    for (int cc = 0; cc < 8; ++cc) {
                        float4 v = *(const float4*)(ub + cc * 4);
                        uu[cc * 4] = v.x; uu[cc * 4 + 1] = v.y; uu[cc * 4 + 2] = v.z; uu[cc * 4 + 3] = v.w;
                    }
                    float p0e = 0.f, p0o = 0.f, p1e = 0.f, p1o = 0.f;
#pragma unroll
                    for (int k = 0; k < 32; k += 2) {
                        p0e = fmaf(uu[k], V0[k], p0e);
                        p1e = fmaf(uu[k], V1[k], p1e);
                        p0o = fmaf(uu[k + 1], V0[k + 1], p0o);
                        p1o = fmaf(uu[k + 1], V1[k + 1], p1o);
                    }
                    float w0 = quad_add(p0e + p0o);
                    float w1 = quad_add(p1e + p1o);
                    float rinv = __builtin_amdgcn_rcpf(u00);
                    OFF += log2f(u00);
                    S0_ = w0 * rinv;   // beta has no outer emission factor
                    S1_ = w1 * rinv;
                }
                // always rewrite y with the NEXT step's emission e_{t-1}
                float2 em = emc[r];
                if (s == 0) {
                    sm.ubuf[cur ^ 1][padw] = exp2f(em.x * L2E) * S0_;
                    sm.ubuf[cur ^ 1][padw + 1] = exp2f(em.y * L2E) * S1_;
                }
                cur ^= 1;
                step_barrier();
            }
#pragma unroll
            for (int d = 0; d < CH; ++d) emc[d] = emn[d];
        }
        if (s == 0) {
            out[b * TT + 128 + j0] = S0_;      // beta_255 (exp domain)
            out[b * TT + 128 + j0 + 1] = S1_;
        }
        if (tid == 0) out[b * TT + 385] = OFF;
    } else {
        // ---------- viterbi forward, FULL t = 0..511 (exact decode) ----------
        const int b = bid - 2 * BB;
        const float* lrow = logits + (size_t)b * TT * KK;
        float* hist = shist + (size_t)b * TT * KK;
        unsigned long long mb[8];
#pragma unroll
        for (int c = 0; c < 8; ++c) mb[c] = __ballot(mask[b * TT + c * 64 + lane] != 0);
        float T0[32], T1[32];
#pragma unroll
        for (int k = 0; k < 32; k++) {
            T0[k] = trans[(s * 32 + k) * KK + j0];
            T1[k] = trans[(s * 32 + k) * KK + j0 + 1];
        }
        float s0_ = startT[j0] + lrow[j0];
        float s1_ = startT[j0 + 1] + lrow[j0 + 1];
        if (s == 0) {
            sm.ubuf[0][padw] = s0_;
            sm.ubuf[0][padw + 1] = s1_;
        } else if (s == 1) {
            *(float2*)(hist + j0) = make_float2(s0_, s1_);
        }
        float2 emc[CH], emn[CH], hb[CH];
#pragma unroll
        for (int d = 0; d < CH; ++d) emc[d] = *(const float2*)(lrow + (size_t)d * KK + j0);
        __syncthreads();
        int cur = 0;
        for (int c = 0; c < NCV; ++c) {
#pragma unroll
            for (int r = 0; r < CH; ++r) {
                const int t = c * CH + r;
                if (r == 0 && c + 1 < NCV) {
#pragma unroll
                    for (int d = 0; d < CH; ++d)
                        emn[d] = *(const float2*)(lrow + (size_t)((c + 1) * CH + d) * KK + j0);
                }
                if (t > 0 && ((mb[t >> 6] >> (t & 63)) & 1ull)) {
                    const float* ub = &sm.ubuf[cur][s * 36];
                    float uu[32];
#pragma unroll
                    for (int cc = 0; cc < 8; ++cc) {
                        float4 v = *(const float4*)(ub + cc * 4);
                        uu[cc * 4] = v.x; uu[cc * 4 + 1] = v.y; uu[cc * 4 + 2] = v.z; uu[cc * 4 + 3] = v.w;
                    }
                    float2 em = emc[r];
                    float m0a = -3.0e38f, m0b = -3.0e38f, m1a = -3.0e38f, m1b = -3.0e38f;
#pragma unroll
                    for (int k = 0; k < 32; k += 4) {
                        m0a = fmaxf(m0a, fmaxf(uu[k] + T0[k], uu[k + 1] + T0[k + 1]));
                        m0b = fmaxf(m0b, fmaxf(uu[k + 2] + T0[k + 2], uu[k + 3] + T0[k + 3]));
                        m1a = fmaxf(m1a, fmaxf(uu[k] + T1[k], uu[k + 1] + T1[k + 1]));
                        m1b = fmaxf(m1b, fmaxf(uu[k + 2] + T1[k + 2], uu[k + 3] + T1[k + 3]));
                    }
                    float m0 = quad_max(fmaxf(m0a, m0b));
                    float m1 = quad_max(fmaxf(m1a, m1b));
                    s0_ = m0 + em.x;
                    s1_ = m1 + em.y;
                    if (s == 0) {
                        sm.ubuf[cur ^ 1][padw] = s0_;
                        sm.ubuf[cur ^ 1][padw + 1] = s1_;
                    }
                    cur ^= 1;
                }
                hb[r] = make_float2(s0_, s1_);
                step_barrier();
            }
            // flush this chunk's history rows (stores drain lazily; no vmcnt
            // wait at step barriers anymore)
            if (s == 1) {
#pragma unroll
                for (int r = 0; r < CH; ++r)
                    *(float2*)(hist + (size_t)(c * CH + r) * KK + j0) = hb[r];
            }
#pragma unroll
            for (int d = 0; d < CH; ++d) emc[d] = emn[d];
        }
    }
}

// -------------------- Kernel C: parallel backpointer recompute --------------------
// bp[t][j] = argmax_i(f_{t-1}[i] + trans[i][j]) — exact reference objective.
__global__ __launch_bounds__(256) void bp_k(const float* __restrict__ shist,
                                            const float* __restrict__ trans,
                                            const int* __restrict__ mask,
                                            unsigned char* __restrict__ bp) {
    const int t = blockIdx.x + 1;
    const int tid = threadIdx.x;
    const int j = tid & 127, bg = tid >> 7;
    __shared__ float sc[BB][KK];
#pragma unroll
    for (int r = 0; r < 4; ++r) {
        int f = tid + r * 256;
        int bb2 = f >> 5, c4 = (f & 31) * 4;
        *(float4*)&sc[bb2][c4] = *(const float4*)&shist[(size_t)bb2 * TT * KK + (size_t)(t - 1) * KK + c4];
    }
    __syncthreads();
    float m[16];
    int idx[16];
#pragma unroll
    for (int c = 0; c < 16; c++) { m[c] = -3.0e38f; idx[c] = 0; }
    for (int i4 = 0; i4 < 32; ++i4) {
        const int ib = i4 * 4;
        float tr0 = trans[(ib + 0) * KK + j];
        float tr1 = trans[(ib + 1) * KK + j];
        float tr2 = trans[(ib + 2) * KK + j];
        float tr3 = trans[(ib + 3) * KK + j];
#pragma unroll
        for (int c = 0; c < 16; c++) {
            float4 s4 = *(const float4*)&sc[bg + 2 * c][ib];
            float c0 = s4.x + tr0, c1 = s4.y + tr1, c2 = s4.z + tr2, c3 = s4.w + tr3;
            if (c0 > m[c]) { m[c] = c0; idx[c] = ib; }
            if (c1 > m[c]) { m[c] = c1; idx[c] = ib + 1; }
            if (c2 > m[c]) { m[c] = c2; idx[c] = ib + 2; }
            if (c3 > m[c]) { m[c] = c3; idx[c] = ib + 3; }
        }
    }
#pragma unroll
    for (int c = 0; c < 16; c++) {
        int bb2 = bg + 2 * c;
        int v = idx[c];
        if (mask[bb2 * TT + t] == 0) v = j;
        bp[(size_t)bb2 * TT * KK + (size_t)t * KK + j] = (unsigned char)v;
    }
}

// -------------------- Kernel D: backtrace via 8-wave register relay ----------
// Also combines the bidirectional logZ (seamA.seamB dot) into the loss.
__global__ __launch_bounds__(512) void bt_k(const float* __restrict__ shist,
                                            const float* __restrict__ endT,
                                            const unsigned char* __restrict__ bp,
                                            float* __restrict__ out) {
    const int b = blockIdx.x;
    const int tid = threadIdx.x;
    const int lane = tid & 63, w = tid >> 6;
    __shared__ float cb[128];
    __shared__ float pb[128];
    __shared__ int tagbuf[512];
    __shared__ int handoff;
    if (tid < 128) {
        cb[tid] = shist[(size_t)b * TT * KK + (size_t)(TT - 1) * KK + tid] + endT[tid];
        pb[tid] = out[b * TT + tid] * out[b * TT + 128 + tid];
    }
    float offA = out[b * TT + 384];
    float offB = out[b * TT + 385];
    float score = out[b * TT + 386];
    unsigned int reg[64];
    const unsigned char* bpb = bp + (size_t)b * TT * KK;
#pragma unroll
    for (int r = 0; r < 64; r++) {
        int t_row = w * 64 + 1 + r;
        unsigned int v = 0;
        if (t_row < TT) v = *(const unsigned short*)(bpb + (size_t)t_row * KK + lane * 2);
        reg[r] = v;
    }
    __syncthreads();
    if (tid == 0) {
        float mm = cb[0];
        int bi = 0;
        for (int i = 1; i < 128; i++)
            if (cb[i] > mm) { mm = cb[i]; bi = i; }
        tagbuf[TT - 1] = bi;
        handoff = bi;
        float sum = 0.0f;
        for (int i = 0; i < 128; i++) sum += pb[i];
        float logZ = (offA + offB + log2f(sum)) * 0.6931471805599453f;
        float llh = score - logZ;
        atomicAdd(out + BB * TT, -llh * (1.0f / 32.0f));
    }
    __syncthreads();
    for (int ph = 7; ph >= 0; --ph) {
        if (w == ph) {
            int tag = handoff;
#pragma unroll
            for (int r = 63; r >= 0; --r) {
                int t_row = ph * 64 + 1 + r;
                if (t_row < TT) {
                    unsigned int vv = (unsigned int)__shfl((int)reg[r], tag >> 1, 64);
                    tag = (int)((vv >> ((tag & 1) * 8)) & 0xffu);
                    if (lane == 0) tagbuf[t_row - 1] = tag;
                }
            }
            if (lane == 0) handoff = tag;
        }
        __syncthreads();
    }
    out[b * TT + tid] = (float)tagbuf[tid];
}

// -------------------- launch --------------------
extern "C" void kernel_launch(void* const* d_in, const int* in_sizes, int n_in,
                              void* d_out, int out_size, void* d_ws, size_t ws_size,
                              hipStream_t stream) {
    const float* hid = (const float*)d_in[0];
    const int* mask = (const int*)d_in[1];
    const int* labels = (const int*)d_in[2];
    const float* Wm = (const float*)d_in[3];
    const float* bias = (const float*)d_in[4];
    const float* startT = (const float*)d_in[5];
    const float* endT = (const float*)d_in[6];
    const float* trans = (const float*)d_in[7];
    float* out = (float*)d_out;
    char* ws = (char*)d_ws;

    float* logits = (float*)(ws + WS_LOGITS);
    float* shist = (float*)(ws + WS_SHIST);
    unsigned char* bp = (unsigned char*)(ws + WS_BP);

    gemm_k<<<256, 512, 0, stream>>>(hid, Wm, bias, logits, out + BB * TT);
    scan_k<<<96, 256, 0, stream>>>(logits, mask, labels, startT, endT, trans, shist, out);
    bp_k<<<TT - 1, 256, 0, stream>>>(shist, trans, mask, bp);
    bt_k<<<BB, 512, 0, stream>>>(shist, endT, bp, out);
}